// Round 2
// 2441.907 us; speedup vs baseline: 1.6533x; 1.6533x over previous
//
#include <hip/hip_runtime.h>
#include <hip/hip_bf16.h>
#include <math.h>

#define HW   16384
#define WD   128
#define DIM  384
#define NB   8
#define NH   8
#define NC   48
#define NPIX (NB*HW)        // 131072
#define MAT  (DIM*DIM)      // 147456

typedef __hip_bfloat16 bf16;
typedef short s16x8 __attribute__((ext_vector_type(8)));
typedef float f32x4 __attribute__((ext_vector_type(4)));

__device__ __forceinline__ float b2f(bf16 x){ return __bfloat162float(x); }
__device__ __forceinline__ bf16  f2b(float x){ return __float2bfloat16(x); }
__device__ __forceinline__ unsigned short f2bu(float x){
  bf16 b = __float2bfloat16(x);
  unsigned short u;
  __builtin_memcpy(&u, &b, 2);
  return u;
}

// ---------------- zero small atomic targets ----------------
__global__ void k_zero(float* p, int n){
  int i = blockIdx.x*256 + threadIdx.x;
  if(i < n) p[i] = 0.f;
}

// ---------------- LayerNorm stats (per pixel over 384 channels) ----------------
__global__ __launch_bounds__(256) void k_stats(const float* __restrict__ T,
                                               const float* __restrict__ C,
                                               float* __restrict__ mu,
                                               float* __restrict__ rstd){
  int t = threadIdx.x;
  int P = blockIdx.x*256 + t;                 // global pixel 0..131071
  const float* src = (blockIdx.y == 0) ? T : C;
  int b = P >> 14, p = P & (HW-1);
  const float* base = src + (size_t)b*DIM*HW + p;
  float s = 0.f, ss = 0.f;
  for(int c = 0; c < DIM; c++){
    float v = base[(size_t)c*HW];
    s += v; ss += v*v;
  }
  float m   = s * (1.f/DIM);
  float var = ss * (1.f/DIM) - m*m;
  float rs  = rsqrtf(var + 1e-5f);
  int o = blockIdx.y*NPIX + P;
  mu[o] = m; rstd[o] = rs;
}

// ---------------- fold LN affine into conv weights (bf16 out) ----------------
// W'[o,c] = bf16(W[o,c]*lnw[c]);  c1[o] = sum_c W[o,c]*lnb[c] + convb[o];
// c2[o] = sum_c b2f(W'[o,c])  (rounded weights, so the mean-fold matches the MFMA exactly)
__global__ void k_prep(const float* tq_w, const float* ck_w, const float* cv_w,
                       const float* tq_b, const float* ck_b, const float* cv_b,
                       const float* tn_w, const float* tn_b,
                       const float* cn_w, const float* cn_b,
                       bf16* Wpb, float* c1, float* c2){
  int o = blockIdx.x, conv = blockIdx.y, t = threadIdx.x;
  const float* W  = conv==0 ? tq_w : (conv==1 ? ck_w : cv_w);
  const float* cb = conv==0 ? tq_b : (conv==1 ? ck_b : cv_b);
  const float* lw = conv==0 ? tn_w : cn_w;
  const float* lb = conv==0 ? tn_b : cn_b;
  float s1 = 0.f, s2 = 0.f;
  for(int c = t; c < DIM; c += 64){
    float w  = W[o*DIM + c];
    float wp = w * lw[c];
    bf16 wb  = f2b(wp);
    Wpb[conv*MAT + o*DIM + c] = wb;
    s1 += w * lb[c];
    s2 += b2f(wb);
  }
  for(int off = 32; off; off >>= 1){ s1 += __shfl_down(s1, off); s2 += __shfl_down(s2, off); }
  if(t == 0){ c1[conv*DIM + o] = s1 + cb[o]; c2[conv*DIM + o] = s2; }
}

// ---------------- MFMA GEMM: 128x128 tile, 4 waves (2x2), 4x4 16x16 frags, BK=32 ----
// MODE 0: out[o,p] = rs*(W' @ x)[o,p] + c1[o] - mu*rs*c2[o]  -> bf16 (LN folded; B = fp32 input)
// MODE 1: out[o,p] = (W2[b] @ v1)[o,p] + proj_b[o] + resid   -> fp32 (B = bf16 v1)
// A layout in LDS: [kb][oo][j] bf16, byte addr (kb*2048 + oo*16) ^ (kb<<5)
// B layout in LDS: [kb][pp][j] bf16, byte addr (kb*2048 + pp*16 + j*2) ^ (((pp>>3)&7)<<4)
// a_frag: lane l holds A[oo = base+(l&15)][k = (l>>4)*8 + j]; b_frag mirrored; D: col=l&15, row=(l>>4)*4+r
template<int MODE>
__global__ __launch_bounds__(256) void k_gmm(
    const float* __restrict__ Bf, const bf16* __restrict__ Bh,
    const unsigned short* __restrict__ A,
    const float* __restrict__ bias, const float* __restrict__ c2,
    const float* __restrict__ mu, const float* __restrict__ rstd,
    const float* __restrict__ resid,
    bf16* __restrict__ dsth, float* __restrict__ dstf){
  __shared__ unsigned short As[4096];   // 8 KB
  __shared__ unsigned short Bs[4096];   // 8 KB
  const int t = threadIdx.x;
  const int l = t & 63;
  const int w = t >> 6;
  const int wr = w >> 1, wc = w & 1;
  const int b = blockIdx.z;
  const int o0 = blockIdx.y*128, p0 = blockIdx.x*128;
  const unsigned short* Aw = A + (MODE==1 ? (size_t)b*MAT : (size_t)0);

  f32x4 zero = {0.f, 0.f, 0.f, 0.f};
  f32x4 acc[4][4];
  #pragma unroll
  for(int m = 0; m < 4; m++)
    #pragma unroll
    for(int n = 0; n < 4; n++) acc[m][n] = zero;

  const int a_kb = t & 3, a_o = t >> 2;   // A staging: kb 0..3, o row 0..63 (+64 round 2)
  const int b_cl = t >> 4;                // B staging: c_loc 0..15 (+16 round 2)
  const int b_p8 = (t & 15)*8;            // B staging: 8-pixel chunk
  const int kbr = l >> 4;                 // fragment k-block
  const int lr  = l & 15;

  for(int c0 = 0; c0 < DIM; c0 += 32){
    // ---- stage A (reg -> LDS, b128 writes, kb-xor keeps writes+reads ~2-way)
    #pragma unroll
    for(int r = 0; r < 2; r++){
      int oo = a_o + 64*r;
      s16x8 av = *(const s16x8*)(Aw + (size_t)(o0 + oo)*DIM + c0 + a_kb*8);
      int ad = (a_kb*2048 + oo*16) ^ (a_kb<<5);
      *(s16x8*)((char*)As + ad) = av;
    }
    // ---- stage B with transpose (coalesced global read along p, swizzled u16 scatter)
    #pragma unroll
    for(int r = 0; r < 2; r++){
      int cl = b_cl + 16*r;
      int c  = c0 + cl;
      unsigned short vals[8];
      if(MODE == 0){
        const float* src = Bf + ((size_t)(b*DIM + c))*HW + p0 + b_p8;
        float4 x0 = *(const float4*)src;
        float4 x1 = *(const float4*)(src + 4);
        vals[0]=f2bu(x0.x); vals[1]=f2bu(x0.y); vals[2]=f2bu(x0.z); vals[3]=f2bu(x0.w);
        vals[4]=f2bu(x1.x); vals[5]=f2bu(x1.y); vals[6]=f2bu(x1.z); vals[7]=f2bu(x1.w);
      } else {
        const unsigned short* src = (const unsigned short*)Bh + ((size_t)(b*DIM + c))*HW + p0 + b_p8;
        s16x8 v = *(const s16x8*)src;
        #pragma unroll
        for(int j = 0; j < 8; j++) vals[j] = (unsigned short)v[j];
      }
      int base = (cl>>3)*2048 + (cl&7)*2;
      #pragma unroll
      for(int j8 = 0; j8 < 8; j8++){
        int pp = b_p8 + j8;
        int ad = (base + pp*16) ^ (((pp>>3)&7)<<4);
        *(unsigned short*)((char*)Bs + ad) = vals[j8];
      }
    }
    __syncthreads();
    // ---- fragments + MFMA
    s16x8 af[4], bv[4];
    #pragma unroll
    for(int m = 0; m < 4; m++){
      int oo = wr*64 + m*16 + lr;
      int ad = (kbr*2048 + oo*16) ^ (kbr<<5);
      af[m] = *(const s16x8*)((const char*)As + ad);
    }
    #pragma unroll
    for(int n = 0; n < 4; n++){
      int pp = wc*64 + n*16 + lr;
      int ad = (kbr*2048 + pp*16) ^ (((pp>>3)&7)<<4);
      bv[n] = *(const s16x8*)((const char*)Bs + ad);
    }
    #pragma unroll
    for(int m = 0; m < 4; m++)
      #pragma unroll
      for(int n = 0; n < 4; n++)
        acc[m][n] = __builtin_amdgcn_mfma_f32_16x16x32_bf16(af[m], bv[n], acc[m][n], 0, 0, 0);
    __syncthreads();
  }

  // ---- epilogue (verified D layout: col = l&15, row = (l>>4)*4 + r)
  #pragma unroll
  for(int m = 0; m < 4; m++){
    int ob = o0 + wr*64 + m*16 + (l>>4)*4;
    #pragma unroll
    for(int n = 0; n < 4; n++){
      int p = p0 + wc*64 + n*16 + (l&15);
      #pragma unroll
      for(int r4 = 0; r4 < 4; r4++){
        int o = ob + r4;
        size_t oidx = ((size_t)(b*DIM + o))*HW + p;
        float v = acc[m][n][r4];
        if(MODE == 0){
          int P = b*HW + p;
          float rs = rstd[P], mm = mu[P];
          dsth[oidx] = f2b(rs*v + bias[o] - mm*rs*c2[o]);
        } else {
          dstf[oidx] = v + bias[o] + resid[oidx];
        }
      }
    }
  }
}

// ---------------- depthwise 3x3, SAME, NCHW; optional sumsq for l2norm fold ----------------
__global__ __launch_bounds__(256) void k_dw(const bf16* __restrict__ src, bf16* __restrict__ dst,
                                            const float* __restrict__ dw, const float* __restrict__ db,
                                            float* __restrict__ nrm){
  __shared__ float red[4];
  int t = threadIdx.x;
  int c = blockIdx.y, b = blockIdx.z;
  int p = blockIdx.x*256 + t;
  int y = p >> 7, x = p & 127;
  size_t base = (size_t)(b*DIM + c)*HW;
  float w[9];
  #pragma unroll
  for(int i = 0; i < 9; i++) w[i] = dw[c*9 + i];
  float s = db[c];
  #pragma unroll
  for(int dy = 0; dy < 3; dy++){
    int yy = y + dy - 1;
    if(yy < 0 || yy > 127) continue;
    #pragma unroll
    for(int dx = 0; dx < 3; dx++){
      int xx = x + dx - 1;
      if(xx < 0 || xx > 127) continue;
      s = fmaf(w[dy*3+dx], b2f(src[base + yy*WD + xx]), s);
    }
  }
  dst[base + p] = f2b(s);
  if(nrm){
    float v = s*s;
    for(int off = 32; off; off >>= 1) v += __shfl_down(v, off);
    if((t & 63) == 0) red[t >> 6] = v;
    __syncthreads();
    if(t == 0) atomicAdd(&nrm[b*DIM + c], red[0]+red[1]+red[2]+red[3]);
  }
}

// ---------------- attn = q @ k^T over n (unnormalized; norms folded later) ----------------
__global__ __launch_bounds__(64) void k_attn(const bf16* __restrict__ q, const bf16* __restrict__ k,
                                             float* __restrict__ attn){
  __shared__ float qs[48][68];
  __shared__ float kss[48][68];
  int t = threadIdx.x;
  int split = blockIdx.x;                 // 16-way K split
  int h = blockIdx.y, b = blockIdx.z;
  int tx = t & 7, ty = t >> 3;
  int c0 = ty*6, d0 = tx*6;               // 6x6 outputs per thread
  float acc[6][6] = {};
  size_t rb = (size_t)(b*DIM + h*NC)*HW;
  int n0beg = split*1024;
  for(int n0 = n0beg; n0 < n0beg + 1024; n0 += 64){
    for(int i = 0; i < 48; i++){
      qs [i][t] = b2f(q[rb + (size_t)i*HW + n0 + t]);
      kss[i][t] = b2f(k[rb + (size_t)i*HW + n0 + t]);
    }
    __syncthreads();
    for(int nn = 0; nn < 64; nn += 4){
      float4 qa[6], kb[6];
      #pragma unroll
      for(int i = 0; i < 6; i++){
        qa[i] = *(const float4*)&qs [c0+i][nn];
        kb[i] = *(const float4*)&kss[d0+i][nn];
      }
      #pragma unroll
      for(int i = 0; i < 6; i++)
        #pragma unroll
        for(int j = 0; j < 6; j++){
          acc[i][j] = fmaf(qa[i].x, kb[j].x, acc[i][j]);
          acc[i][j] = fmaf(qa[i].y, kb[j].y, acc[i][j]);
          acc[i][j] = fmaf(qa[i].z, kb[j].z, acc[i][j]);
          acc[i][j] = fmaf(qa[i].w, kb[j].w, acc[i][j]);
        }
    }
    __syncthreads();
  }
  float* ab = attn + (size_t)(b*NH + h)*NC*NC;
  #pragma unroll
  for(int i = 0; i < 6; i++)
    #pragma unroll
    for(int j = 0; j < 6; j++)
      atomicAdd(&ab[(c0+i)*NC + d0+j], acc[i][j]);
}

// ---------------- P = sum_i a_i * softmax(mask_i(attn_scaled)) ----------------
__global__ void k_pmat(const float* __restrict__ attn, const float* __restrict__ nq,
                       const float* __restrict__ nk, const float* __restrict__ tptr,
                       const float* __restrict__ a1p, const float* __restrict__ a2p,
                       const float* __restrict__ a3p, const float* __restrict__ a4p,
                       float* __restrict__ P){
  int t = threadIdx.x;
  int h = blockIdx.x, b = blockIdx.y;
  __shared__ float nkv[48];
  if(t < 48) nkv[t] = fmaxf(sqrtf(nk[b*DIM + h*NC + t]), 1e-12f);
  __syncthreads();
  if(t >= 48) return;
  int c = t;
  float temp = tptr[0];
  float nqc = fmaxf(sqrtf(nq[b*DIM + h*NC + c]), 1e-12f);
  const float* row = attn + ((size_t)(b*NH + h)*NC + c)*NC;
  float r[48], s[48];
  for(int d = 0; d < 48; d++){
    float v = row[d] * temp / (nqc * nkv[d]);
    r[d] = v; s[d] = v;
  }
  // insertion sort descending (48 elems, tiny kernel)
  for(int i = 1; i < 48; i++){
    float key = s[i]; int j = i-1;
    while(j >= 0 && s[j] < key){ s[j+1] = s[j]; j--; }
    s[j+1] = key;
  }
  float m  = s[0];
  float t1 = s[23], t2 = s[31], t3 = s[35], t4 = s[37];   // k-th largest, k=24/32/36/38
  float d1 = 0.f, d2 = 0.f, d3 = 0.f, d4 = 0.f;
  for(int d = 0; d < 48; d++){
    float e = expf(r[d] - m);
    s[d] = e;                     // reuse as exp cache
    if(r[d] >= t1) d1 += e;
    if(r[d] >= t2) d2 += e;
    if(r[d] >= t3) d3 += e;
    if(r[d] >= t4) d4 += e;
  }
  float w1 = a1p[0]/d1, w2 = a2p[0]/d2, w3 = a3p[0]/d3, w4 = a4p[0]/d4;
  float* Pr = P + ((size_t)(b*NH + h)*NC + c)*NC;
  for(int d = 0; d < 48; d++){
    float wsum = 0.f;
    if(r[d] >= t1) wsum += w1;
    if(r[d] >= t2) wsum += w2;
    if(r[d] >= t3) wsum += w3;
    if(r[d] >= t4) wsum += w4;
    Pr[d] = s[d] * wsum;
  }
}

// ---------------- W2[b,o,h*48+d] = sum_c projW[o,h*48+c] * P[b,h,c,d]  (bf16 out) ----------------
__global__ __launch_bounds__(384) void k_w2(const float* __restrict__ Wp, const float* __restrict__ P,
                                            bf16* __restrict__ W2){
  int t = threadIdx.x;            // 0..383 -> (h,d)
  int o = blockIdx.x, b = blockIdx.y;
  int h = t / 48, d = t % 48;
  const float* Pb = P + (size_t)(b*NH + h)*NC*NC + d;
  const float* Wr = Wp + o*DIM + h*NC;
  float s = 0.f;
  for(int c = 0; c < 48; c++) s = fmaf(Wr[c], Pb[c*NC], s);
  W2[((size_t)b*DIM + o)*DIM + t] = f2b(s);
}

extern "C" void kernel_launch(void* const* d_in, const int* in_sizes, int n_in,
                              void* d_out, int out_size, void* d_ws, size_t ws_size,
                              hipStream_t stream){
  const float* TEin = (const float*)d_in[0];
  const float* CEin = (const float*)d_in[1];
  const float* tn_w = (const float*)d_in[2];
  const float* tn_b = (const float*)d_in[3];
  const float* cn_w = (const float*)d_in[4];
  const float* cn_b = (const float*)d_in[5];
  const float* tq_w = (const float*)d_in[6];
  const float* tq_b = (const float*)d_in[7];
  const float* tq_dw= (const float*)d_in[8];
  const float* tq_db= (const float*)d_in[9];
  const float* ck_w = (const float*)d_in[10];
  const float* ck_b = (const float*)d_in[11];
  const float* ck_dw= (const float*)d_in[12];
  const float* ck_db= (const float*)d_in[13];
  const float* cv_w = (const float*)d_in[14];
  const float* cv_b = (const float*)d_in[15];
  const float* cv_dw= (const float*)d_in[16];
  const float* cv_db= (const float*)d_in[17];
  const float* temp = (const float*)d_in[18];
  const float* pj_w = (const float*)d_in[19];
  const float* pj_b = (const float*)d_in[20];
  const float* a1   = (const float*)d_in[21];
  const float* a2   = (const float*)d_in[22];
  const float* a3   = (const float*)d_in[23];
  const float* a4   = (const float*)d_in[24];

  char* ws = (char*)d_ws;
  const size_t S2 = (size_t)NB*DIM*HW*2;       // one bf16 tensor: 100,663,296 B
  bf16* q0 = (bf16*)(ws);
  bf16* k0 = (bf16*)(ws +   S2);
  bf16* v0 = (bf16*)(ws + 2*S2);
  bf16* q1 = (bf16*)(ws + 3*S2);
  bf16* k1 = (bf16*)(ws);          // reuses q0 (dead after dw-q)
  bf16* v1 = (bf16*)(ws +   S2);   // reuses k0 (dead after dw-k)
  char* sm = ws + 4*S2;
  float* mu   = (float*)(sm);                      // 2*131072 fp32
  float* rstd = (float*)(sm + 1048576);
  bf16*  Wpb  = (bf16*) (sm + 2097152);            // 3*384*384 bf16 (fits old fp32 slot)
  float* c1   = (float*)(sm + 3866624);            // 3*384
  float* c2   = (float*)(sm + 3871232);            // 3*384
  float* nq   = (float*)(sm + 3875840);            // 8*384
  float* nk   = (float*)(sm + 3888128);            // 8*384
  float* attn = (float*)(sm + 3900416);            // 64*48*48
  float* P    = (float*)(sm + 4490240);            // 64*48*48
  bf16*  W2b  = (bf16*) (sm + 5080064);            // 8*384*384 bf16 (fits old fp32 slot)

  // zero atomic targets (nq, nk, attn are contiguous: 153600 floats)
  k_zero<<<dim3(600), 256, 0, stream>>>(nq, 153600);
  // LN stats for both tensors
  k_stats<<<dim3(512, 2), 256, 0, stream>>>(TEin, CEin, mu, rstd);
  // fold LN into conv weights (bf16)
  k_prep<<<dim3(384, 3), 64, 0, stream>>>(tq_w, ck_w, cv_w, tq_b, ck_b, cv_b,
                                          tn_w, tn_b, cn_w, cn_b, Wpb, c1, c2);
  // conv1x1 (LN folded) via MFMA: q from T stats, k/v from C stats
  k_gmm<0><<<dim3(128,3,8), 256, 0, stream>>>(TEin, nullptr, (const unsigned short*)Wpb,
                                              c1, c2, mu, rstd, nullptr, q0, nullptr);
  k_gmm<0><<<dim3(128,3,8), 256, 0, stream>>>(CEin, nullptr, (const unsigned short*)(Wpb+MAT),
                                              c1+DIM, c2+DIM, mu+NPIX, rstd+NPIX, nullptr, k0, nullptr);
  k_gmm<0><<<dim3(128,3,8), 256, 0, stream>>>(CEin, nullptr, (const unsigned short*)(Wpb+2*MAT),
                                              c1+2*DIM, c2+2*DIM, mu+NPIX, rstd+NPIX, nullptr, v0, nullptr);
  // depthwise 3x3 (+ sumsq accumulation for q,k norms)
  k_dw<<<dim3(64,384,8), 256, 0, stream>>>(q0, q1, tq_dw, tq_db, nq);
  k_dw<<<dim3(64,384,8), 256, 0, stream>>>(k0, k1, ck_dw, ck_db, nk);
  k_dw<<<dim3(64,384,8), 256, 0, stream>>>(v0, v1, cv_dw, cv_db, nullptr);
  // attn (unnormalized), 16-way K split with atomic accumulation
  k_attn<<<dim3(16,8,8), 64, 0, stream>>>(q1, k1, attn);
  // combined masked-softmax matrix P (norms + temperature folded here)
  k_pmat<<<dim3(8,8), 64, 0, stream>>>(attn, nq, nk, temp, a1, a2, a3, a4, P);
  // W2 = projW (per-head) @ P  (bf16 out)
  k_w2<<<dim3(384,8), 384, 0, stream>>>(pj_w, P, W2b);
  // fused (P·v + proj + residual) as one MFMA GEMM: out = W2[b] @ v1 + proj_b + C_E_input
  k_gmm<1><<<dim3(128,3,8), 256, 0, stream>>>(nullptr, v1, (const unsigned short*)W2b,
                                              pj_b, nullptr, nullptr, nullptr, CEin, nullptr, (float*)d_out);
}

// Round 3
// 1416.259 us; speedup vs baseline: 2.8506x; 1.7242x over previous
//
#include <hip/hip_runtime.h>
#include <hip/hip_bf16.h>
#include <math.h>

#define HW   16384
#define WD   128
#define DIM  384
#define NB   8
#define NH   8
#define NC   48
#define NPIX (NB*HW)        // 131072
#define MAT  (DIM*DIM)      // 147456

typedef __hip_bfloat16 bf16;
typedef short s16x8 __attribute__((ext_vector_type(8)));
typedef float f32x4 __attribute__((ext_vector_type(4)));

__device__ __forceinline__ float b2f(bf16 x){ return __bfloat162float(x); }
__device__ __forceinline__ bf16  f2b(float x){ return __float2bfloat16(x); }
__device__ __forceinline__ unsigned short f2bu(float x){
  bf16 b = __float2bfloat16(x);
  unsigned short u;
  __builtin_memcpy(&u, &b, 2);
  return u;
}
__device__ __forceinline__ float u2f(unsigned short u){
  union{ unsigned int i; float f; } x;
  x.i = ((unsigned int)u) << 16;
  return x.f;
}

// ---------------- zero small atomic targets ----------------
__global__ void k_zero(float* p, int n){
  int i = blockIdx.x*256 + threadIdx.x;
  if(i < n) p[i] = 0.f;
}

// ---------------- LayerNorm stats (per pixel over 384 channels) ----------------
__global__ __launch_bounds__(256) void k_stats(const float* __restrict__ T,
                                               const float* __restrict__ C,
                                               float* __restrict__ mu,
                                               float* __restrict__ rstd){
  int t = threadIdx.x;
  int P = blockIdx.x*256 + t;                 // global pixel 0..131071
  const float* src = (blockIdx.y == 0) ? T : C;
  int b = P >> 14, p = P & (HW-1);
  const float* base = src + (size_t)b*DIM*HW + p;
  float s = 0.f, ss = 0.f;
  for(int c = 0; c < DIM; c++){
    float v = base[(size_t)c*HW];
    s += v; ss += v*v;
  }
  float m   = s * (1.f/DIM);
  float var = ss * (1.f/DIM) - m*m;
  float rs  = rsqrtf(var + 1e-5f);
  int o = blockIdx.y*NPIX + P;
  mu[o] = m; rstd[o] = rs;
}

// ---------------- fold LN affine into conv weights (bf16 out) ----------------
// W'[o,c] = bf16(W[o,c]*lnw[c]);  c1[o] = sum_c W[o,c]*lnb[c] + convb[o];
// c2[o] = sum_c b2f(W'[o,c])  (rounded weights, so the mean-fold matches the MFMA exactly)
__global__ void k_prep(const float* tq_w, const float* ck_w, const float* cv_w,
                       const float* tq_b, const float* ck_b, const float* cv_b,
                       const float* tn_w, const float* tn_b,
                       const float* cn_w, const float* cn_b,
                       bf16* Wpb, float* c1, float* c2){
  int o = blockIdx.x, conv = blockIdx.y, t = threadIdx.x;
  const float* W  = conv==0 ? tq_w : (conv==1 ? ck_w : cv_w);
  const float* cb = conv==0 ? tq_b : (conv==1 ? ck_b : cv_b);
  const float* lw = conv==0 ? tn_w : cn_w;
  const float* lb = conv==0 ? tn_b : cn_b;
  float s1 = 0.f, s2 = 0.f;
  for(int c = t; c < DIM; c += 64){
    float w  = W[o*DIM + c];
    float wp = w * lw[c];
    bf16 wb  = f2b(wp);
    Wpb[conv*MAT + o*DIM + c] = wb;
    s1 += w * lb[c];
    s2 += b2f(wb);
  }
  for(int off = 32; off; off >>= 1){ s1 += __shfl_down(s1, off); s2 += __shfl_down(s2, off); }
  if(t == 0){ c1[conv*DIM + o] = s1 + cb[o]; c2[conv*DIM + o] = s2; }
}

// ---------------- MFMA GEMM: 128x128 tile, 4 waves (2x2), 4x4 16x16 frags, BK=32 ----
// MODE 0: out[o,p] = rs*(W' @ x)[o,p] + c1[o] - mu*rs*c2[o]  -> bf16 (LN folded; B = fp32 input)
// MODE 1: out[o,p] = (W2[b] @ v1)[o,p] + proj_b[o] + resid   -> fp32 (B = bf16 v1)
// A layout in LDS: [kb][oo][j] bf16, byte addr (kb*2048 + oo*16) ^ (kb<<5)
// B layout in LDS: [kb][pp][j] bf16, byte addr (kb*2048 + pp*16 + j*2) ^ (((pp>>3)&7)<<4)
// a_frag: lane l holds A[oo = base+(l&15)][k = (l>>4)*8 + j]; b_frag mirrored; D: col=l&15, row=(l>>4)*4+r
template<int MODE>
__global__ __launch_bounds__(256) void k_gmm(
    const float* __restrict__ Bf, const bf16* __restrict__ Bh,
    const unsigned short* __restrict__ A,
    const float* __restrict__ bias, const float* __restrict__ c2,
    const float* __restrict__ mu, const float* __restrict__ rstd,
    const float* __restrict__ resid,
    bf16* __restrict__ dsth, float* __restrict__ dstf){
  __shared__ unsigned short As[4096];   // 8 KB
  __shared__ unsigned short Bs[4096];   // 8 KB
  const int t = threadIdx.x;
  const int l = t & 63;
  const int w = t >> 6;
  const int wr = w >> 1, wc = w & 1;
  const int b = blockIdx.z;
  const int o0 = blockIdx.y*128, p0 = blockIdx.x*128;
  const unsigned short* Aw = A + (MODE==1 ? (size_t)b*MAT : (size_t)0);

  f32x4 zero = {0.f, 0.f, 0.f, 0.f};
  f32x4 acc[4][4];
  #pragma unroll
  for(int m = 0; m < 4; m++)
    #pragma unroll
    for(int n = 0; n < 4; n++) acc[m][n] = zero;

  const int a_kb = t & 3, a_o = t >> 2;   // A staging: kb 0..3, o row 0..63 (+64 round 2)
  const int b_cl = t >> 4;                // B staging: c_loc 0..15 (+16 round 2)
  const int b_p8 = (t & 15)*8;            // B staging: 8-pixel chunk
  const int kbr = l >> 4;                 // fragment k-block
  const int lr  = l & 15;

  for(int c0 = 0; c0 < DIM; c0 += 32){
    // ---- stage A (reg -> LDS, b128 writes, kb-xor keeps writes+reads ~2-way)
    #pragma unroll
    for(int r = 0; r < 2; r++){
      int oo = a_o + 64*r;
      s16x8 av = *(const s16x8*)(Aw + (size_t)(o0 + oo)*DIM + c0 + a_kb*8);
      int ad = (a_kb*2048 + oo*16) ^ (a_kb<<5);
      *(s16x8*)((char*)As + ad) = av;
    }
    // ---- stage B with transpose (coalesced global read along p, swizzled u16 scatter)
    #pragma unroll
    for(int r = 0; r < 2; r++){
      int cl = b_cl + 16*r;
      int c  = c0 + cl;
      unsigned short vals[8];
      if(MODE == 0){
        const float* src = Bf + ((size_t)(b*DIM + c))*HW + p0 + b_p8;
        float4 x0 = *(const float4*)src;
        float4 x1 = *(const float4*)(src + 4);
        vals[0]=f2bu(x0.x); vals[1]=f2bu(x0.y); vals[2]=f2bu(x0.z); vals[3]=f2bu(x0.w);
        vals[4]=f2bu(x1.x); vals[5]=f2bu(x1.y); vals[6]=f2bu(x1.z); vals[7]=f2bu(x1.w);
      } else {
        const unsigned short* src = (const unsigned short*)Bh + ((size_t)(b*DIM + c))*HW + p0 + b_p8;
        s16x8 v = *(const s16x8*)src;
        #pragma unroll
        for(int j = 0; j < 8; j++) vals[j] = (unsigned short)v[j];
      }
      int base = (cl>>3)*2048 + (cl&7)*2;
      #pragma unroll
      for(int j8 = 0; j8 < 8; j8++){
        int pp = b_p8 + j8;
        int ad = (base + pp*16) ^ (((pp>>3)&7)<<4);
        *(unsigned short*)((char*)Bs + ad) = vals[j8];
      }
    }
    __syncthreads();
    // ---- fragments + MFMA
    s16x8 af[4], bv[4];
    #pragma unroll
    for(int m = 0; m < 4; m++){
      int oo = wr*64 + m*16 + lr;
      int ad = (kbr*2048 + oo*16) ^ (kbr<<5);
      af[m] = *(const s16x8*)((const char*)As + ad);
    }
    #pragma unroll
    for(int n = 0; n < 4; n++){
      int pp = wc*64 + n*16 + lr;
      int ad = (kbr*2048 + pp*16) ^ (((pp>>3)&7)<<4);
      bv[n] = *(const s16x8*)((const char*)Bs + ad);
    }
    #pragma unroll
    for(int m = 0; m < 4; m++)
      #pragma unroll
      for(int n = 0; n < 4; n++)
        acc[m][n] = __builtin_amdgcn_mfma_f32_16x16x32_bf16(af[m], bv[n], acc[m][n], 0, 0, 0);
    __syncthreads();
  }

  // ---- epilogue (verified D layout: col = l&15, row = (l>>4)*4 + r)
  #pragma unroll
  for(int m = 0; m < 4; m++){
    int ob = o0 + wr*64 + m*16 + (l>>4)*4;
    #pragma unroll
    for(int n = 0; n < 4; n++){
      int p = p0 + wc*64 + n*16 + (l&15);
      #pragma unroll
      for(int r4 = 0; r4 < 4; r4++){
        int o = ob + r4;
        size_t oidx = ((size_t)(b*DIM + o))*HW + p;
        float v = acc[m][n][r4];
        if(MODE == 0){
          int P = b*HW + p;
          float rs = rstd[P], mm = mu[P];
          dsth[oidx] = f2b(rs*v + bias[o] - mm*rs*c2[o]);
        } else {
          dstf[oidx] = v + bias[o] + resid[oidx];
        }
      }
    }
  }
}

// ---------------- depthwise 3x3, SAME, NCHW — LDS-tiled, vectorized ----------------
// Block: 32 rows x 128 cols of one (b,c) plane. Stage 34x128 bf16 in LDS (s16x8 loads),
// each thread computes 16 outputs (2 row-segments of 8 px), vector b128 store.
// Image halo (x=-1/128, y=-1/128) is zero, handled by predication (never stored).
__global__ __launch_bounds__(256) void k_dw(const bf16* __restrict__ src, bf16* __restrict__ dst,
                                            const float* __restrict__ dw, const float* __restrict__ db,
                                            float* __restrict__ nrm){
  __shared__ unsigned short tile[34*136];   // row stride 136 shorts = 272 B (17x16B, aligned)
  __shared__ float red[4];
  int t = threadIdx.x;
  int tb = blockIdx.x;                      // row-tile 0..3
  int c = blockIdx.y, b = blockIdx.z;
  size_t base = (size_t)(b*DIM + c)*HW;
  int y0 = tb*32;
  const unsigned short* sp = (const unsigned short*)src + base;
  // stage 34 rows (y0-1 .. y0+32) x 128 cols
  for(int i = t; i < 544; i += 256){
    int r = i >> 4, ch = i & 15;
    int yy = y0 + r - 1;
    s16x8 v = {};
    if(yy >= 0 && yy < 128) v = *(const s16x8*)(sp + yy*WD + ch*8);
    *(s16x8*)&tile[r*136 + ch*8] = v;
  }
  float w[9];
  #pragma unroll
  for(int i = 0; i < 9; i++) w[i] = dw[c*9 + i];
  float bias = db[c];
  __syncthreads();
  unsigned short* dp = (unsigned short*)dst + base;
  float ssq = 0.f;
  #pragma unroll
  for(int task = 0; task < 2; task++){
    int i = t + task*256;
    int ry = i >> 4, xseg = i & 15;          // output row ry (0..31), 8-px segment
    int xb = xseg*8;
    float v[3][10];
    #pragma unroll
    for(int rr = 0; rr < 3; rr++){
      const unsigned short* row = &tile[(ry+rr)*136];
      s16x8 mid = *(const s16x8*)&row[xb];
      v[rr][0] = (xb == 0)   ? 0.f : u2f(row[xb-1]);
      #pragma unroll
      for(int j = 0; j < 8; j++) v[rr][1+j] = u2f((unsigned short)mid[j]);
      v[rr][9] = (xb == 120) ? 0.f : u2f(row[xb+8]);
    }
    s16x8 outv;
    #pragma unroll
    for(int j = 0; j < 8; j++){
      float s = bias;
      #pragma unroll
      for(int rr = 0; rr < 3; rr++){
        s = fmaf(w[rr*3+0], v[rr][j],   s);
        s = fmaf(w[rr*3+1], v[rr][j+1], s);
        s = fmaf(w[rr*3+2], v[rr][j+2], s);
      }
      ssq = fmaf(s, s, ssq);
      outv[j] = (short)f2bu(s);
    }
    *(s16x8*)(dp + (y0+ry)*WD + xb) = outv;
  }
  if(nrm){
    for(int off = 32; off; off >>= 1) ssq += __shfl_down(ssq, off);
    if((t & 63) == 0) red[t >> 6] = ssq;
    __syncthreads();
    if(t == 0) atomicAdd(&nrm[b*DIM + c], red[0]+red[1]+red[2]+red[3]);
  }
}

// ---------------- attn = q @ k^T over n (unnormalized; norms folded later) ----------------
__global__ __launch_bounds__(64) void k_attn(const bf16* __restrict__ q, const bf16* __restrict__ k,
                                             float* __restrict__ attn){
  __shared__ float qs[48][68];
  __shared__ float kss[48][68];
  int t = threadIdx.x;
  int split = blockIdx.x;                 // 16-way K split
  int h = blockIdx.y, b = blockIdx.z;
  int tx = t & 7, ty = t >> 3;
  int c0 = ty*6, d0 = tx*6;               // 6x6 outputs per thread
  float acc[6][6] = {};
  size_t rb = (size_t)(b*DIM + h*NC)*HW;
  int n0beg = split*1024;
  for(int n0 = n0beg; n0 < n0beg + 1024; n0 += 64){
    for(int i = 0; i < 48; i++){
      qs [i][t] = b2f(q[rb + (size_t)i*HW + n0 + t]);
      kss[i][t] = b2f(k[rb + (size_t)i*HW + n0 + t]);
    }
    __syncthreads();
    for(int nn = 0; nn < 64; nn += 4){
      float4 qa[6], kb[6];
      #pragma unroll
      for(int i = 0; i < 6; i++){
        qa[i] = *(const float4*)&qs [c0+i][nn];
        kb[i] = *(const float4*)&kss[d0+i][nn];
      }
      #pragma unroll
      for(int i = 0; i < 6; i++)
        #pragma unroll
        for(int j = 0; j < 6; j++){
          acc[i][j] = fmaf(qa[i].x, kb[j].x, acc[i][j]);
          acc[i][j] = fmaf(qa[i].y, kb[j].y, acc[i][j]);
          acc[i][j] = fmaf(qa[i].z, kb[j].z, acc[i][j]);
          acc[i][j] = fmaf(qa[i].w, kb[j].w, acc[i][j]);
        }
    }
    __syncthreads();
  }
  float* ab = attn + (size_t)(b*NH + h)*NC*NC;
  #pragma unroll
  for(int i = 0; i < 6; i++)
    #pragma unroll
    for(int j = 0; j < 6; j++)
      atomicAdd(&ab[(c0+i)*NC + d0+j], acc[i][j]);
}

// ---------------- P = sum_i a_i * softmax(mask_i(attn_scaled)) ----------------
__global__ void k_pmat(const float* __restrict__ attn, const float* __restrict__ nq,
                       const float* __restrict__ nk, const float* __restrict__ tptr,
                       const float* __restrict__ a1p, const float* __restrict__ a2p,
                       const float* __restrict__ a3p, const float* __restrict__ a4p,
                       float* __restrict__ P){
  int t = threadIdx.x;
  int h = blockIdx.x, b = blockIdx.y;
  __shared__ float nkv[48];
  if(t < 48) nkv[t] = fmaxf(sqrtf(nk[b*DIM + h*NC + t]), 1e-12f);
  __syncthreads();
  if(t >= 48) return;
  int c = t;
  float temp = tptr[0];
  float nqc = fmaxf(sqrtf(nq[b*DIM + h*NC + c]), 1e-12f);
  const float* row = attn + ((size_t)(b*NH + h)*NC + c)*NC;
  float r[48], s[48];
  for(int d = 0; d < 48; d++){
    float v = row[d] * temp / (nqc * nkv[d]);
    r[d] = v; s[d] = v;
  }
  // insertion sort descending (48 elems, tiny kernel)
  for(int i = 1; i < 48; i++){
    float key = s[i]; int j = i-1;
    while(j >= 0 && s[j] < key){ s[j+1] = s[j]; j--; }
    s[j+1] = key;
  }
  float m  = s[0];
  float t1 = s[23], t2 = s[31], t3 = s[35], t4 = s[37];   // k-th largest, k=24/32/36/38
  float d1 = 0.f, d2 = 0.f, d3 = 0.f, d4 = 0.f;
  for(int d = 0; d < 48; d++){
    float e = expf(r[d] - m);
    s[d] = e;                     // reuse as exp cache
    if(r[d] >= t1) d1 += e;
    if(r[d] >= t2) d2 += e;
    if(r[d] >= t3) d3 += e;
    if(r[d] >= t4) d4 += e;
  }
  float w1 = a1p[0]/d1, w2 = a2p[0]/d2, w3 = a3p[0]/d3, w4 = a4p[0]/d4;
  float* Pr = P + ((size_t)(b*NH + h)*NC + c)*NC;
  for(int d = 0; d < 48; d++){
    float wsum = 0.f;
    if(r[d] >= t1) wsum += w1;
    if(r[d] >= t2) wsum += w2;
    if(r[d] >= t3) wsum += w3;
    if(r[d] >= t4) wsum += w4;
    Pr[d] = s[d] * wsum;
  }
}

// ---------------- W2[b,o,h*48+d] = sum_c projW[o,h*48+c] * P[b,h,c,d]  (bf16 out) ----------------
__global__ __launch_bounds__(384) void k_w2(const float* __restrict__ Wp, const float* __restrict__ P,
                                            bf16* __restrict__ W2){
  int t = threadIdx.x;            // 0..383 -> (h,d)
  int o = blockIdx.x, b = blockIdx.y;
  int h = t / 48, d = t % 48;
  const float* Pb = P + (size_t)(b*NH + h)*NC*NC + d;
  const float* Wr = Wp + o*DIM + h*NC;
  float s = 0.f;
  for(int c = 0; c < 48; c++) s = fmaf(Wr[c], Pb[c*NC], s);
  W2[((size_t)b*DIM + o)*DIM + t] = f2b(s);
}

extern "C" void kernel_launch(void* const* d_in, const int* in_sizes, int n_in,
                              void* d_out, int out_size, void* d_ws, size_t ws_size,
                              hipStream_t stream){
  const float* TEin = (const float*)d_in[0];
  const float* CEin = (const float*)d_in[1];
  const float* tn_w = (const float*)d_in[2];
  const float* tn_b = (const float*)d_in[3];
  const float* cn_w = (const float*)d_in[4];
  const float* cn_b = (const float*)d_in[5];
  const float* tq_w = (const float*)d_in[6];
  const float* tq_b = (const float*)d_in[7];
  const float* tq_dw= (const float*)d_in[8];
  const float* tq_db= (const float*)d_in[9];
  const float* ck_w = (const float*)d_in[10];
  const float* ck_b = (const float*)d_in[11];
  const float* ck_dw= (const float*)d_in[12];
  const float* ck_db= (const float*)d_in[13];
  const float* cv_w = (const float*)d_in[14];
  const float* cv_b = (const float*)d_in[15];
  const float* cv_dw= (const float*)d_in[16];
  const float* cv_db= (const float*)d_in[17];
  const float* temp = (const float*)d_in[18];
  const float* pj_w = (const float*)d_in[19];
  const float* pj_b = (const float*)d_in[20];
  const float* a1   = (const float*)d_in[21];
  const float* a2   = (const float*)d_in[22];
  const float* a3   = (const float*)d_in[23];
  const float* a4   = (const float*)d_in[24];

  char* ws = (char*)d_ws;
  const size_t S2 = (size_t)NB*DIM*HW*2;       // one bf16 tensor: 100,663,296 B
  bf16* q0 = (bf16*)(ws);
  bf16* k0 = (bf16*)(ws +   S2);
  bf16* v0 = (bf16*)(ws + 2*S2);
  bf16* q1 = (bf16*)(ws + 3*S2);
  bf16* k1 = (bf16*)(ws);          // reuses q0 (dead after dw-q)
  bf16* v1 = (bf16*)(ws +   S2);   // reuses k0 (dead after dw-k)
  char* sm = ws + 4*S2;
  float* mu   = (float*)(sm);                      // 2*131072 fp32
  float* rstd = (float*)(sm + 1048576);
  bf16*  Wpb  = (bf16*) (sm + 2097152);            // 3*384*384 bf16 (fits old fp32 slot)
  float* c1   = (float*)(sm + 3866624);            // 3*384
  float* c2   = (float*)(sm + 3871232);            // 3*384
  float* nq   = (float*)(sm + 3875840);            // 8*384
  float* nk   = (float*)(sm + 3888128);            // 8*384
  float* attn = (float*)(sm + 3900416);            // 64*48*48
  float* P    = (float*)(sm + 4490240);            // 64*48*48
  bf16*  W2b  = (bf16*) (sm + 5080064);            // 8*384*384 bf16 (fits old fp32 slot)

  // zero atomic targets (nq, nk, attn are contiguous: 153600 floats)
  k_zero<<<dim3(600), 256, 0, stream>>>(nq, 153600);
  // LN stats for both tensors
  k_stats<<<dim3(512, 2), 256, 0, stream>>>(TEin, CEin, mu, rstd);
  // fold LN into conv weights (bf16)
  k_prep<<<dim3(384, 3), 64, 0, stream>>>(tq_w, ck_w, cv_w, tq_b, ck_b, cv_b,
                                          tn_w, tn_b, cn_w, cn_b, Wpb, c1, c2);
  // conv1x1 (LN folded) via MFMA: q from T stats, k/v from C stats
  k_gmm<0><<<dim3(128,3,8), 256, 0, stream>>>(TEin, nullptr, (const unsigned short*)Wpb,
                                              c1, c2, mu, rstd, nullptr, q0, nullptr);
  k_gmm<0><<<dim3(128,3,8), 256, 0, stream>>>(CEin, nullptr, (const unsigned short*)(Wpb+MAT),
                                              c1+DIM, c2+DIM, mu+NPIX, rstd+NPIX, nullptr, k0, nullptr);
  k_gmm<0><<<dim3(128,3,8), 256, 0, stream>>>(CEin, nullptr, (const unsigned short*)(Wpb+2*MAT),
                                              c1+2*DIM, c2+2*DIM, mu+NPIX, rstd+NPIX, nullptr, v0, nullptr);
  // depthwise 3x3 (+ sumsq accumulation for q,k norms), LDS-tiled
  k_dw<<<dim3(4,384,8), 256, 0, stream>>>(q0, q1, tq_dw, tq_db, nq);
  k_dw<<<dim3(4,384,8), 256, 0, stream>>>(k0, k1, ck_dw, ck_db, nk);
  k_dw<<<dim3(4,384,8), 256, 0, stream>>>(v0, v1, cv_dw, cv_db, nullptr);
  // attn (unnormalized), 16-way K split with atomic accumulation
  k_attn<<<dim3(16,8,8), 64, 0, stream>>>(q1, k1, attn);
  // combined masked-softmax matrix P (norms + temperature folded here)
  k_pmat<<<dim3(8,8), 64, 0, stream>>>(attn, nq, nk, temp, a1, a2, a3, a4, P);
  // W2 = projW (per-head) @ P  (bf16 out)
  k_w2<<<dim3(384,8), 384, 0, stream>>>(pj_w, P, W2b);
  // fused (P·v + proj + residual) as one MFMA GEMM: out = W2[b] @ v1 + proj_b + C_E_input
  k_gmm<1><<<dim3(128,3,8), 256, 0, stream>>>(nullptr, v1, (const unsigned short*)W2b,
                                              pj_b, nullptr, nullptr, nullptr, CEin, nullptr, (float*)d_out);
}

// Round 4
// 1297.873 us; speedup vs baseline: 3.1106x; 1.0912x over previous
//
#include <hip/hip_runtime.h>
#include <hip/hip_bf16.h>
#include <math.h>

#define HW   16384
#define WD   128
#define DIM  384
#define NB   8
#define NH   8
#define NC   48
#define NPIX (NB*HW)        // 131072
#define MAT  (DIM*DIM)      // 147456

typedef __hip_bfloat16 bf16;
typedef short s16x8 __attribute__((ext_vector_type(8)));
typedef float f32x4 __attribute__((ext_vector_type(4)));

__device__ __forceinline__ float b2f(bf16 x){ return __bfloat162float(x); }
__device__ __forceinline__ bf16  f2b(float x){ return __float2bfloat16(x); }
__device__ __forceinline__ unsigned short f2bu(float x){
  bf16 b = __float2bfloat16(x);
  unsigned short u;
  __builtin_memcpy(&u, &b, 2);
  return u;
}
__device__ __forceinline__ float u2f(unsigned short u){
  union{ unsigned int i; float f; } x;
  x.i = ((unsigned int)u) << 16;
  return x.f;
}

// ---------------- zero small atomic targets ----------------
__global__ void k_zero(float* p, int n){
  int i = blockIdx.x*256 + threadIdx.x;
  if(i < n) p[i] = 0.f;
}

// ---------------- LayerNorm stats (per pixel over 384 channels) ----------------
__global__ __launch_bounds__(256) void k_stats(const float* __restrict__ T,
                                               const float* __restrict__ C,
                                               float* __restrict__ mu,
                                               float* __restrict__ rstd){
  int t = threadIdx.x;
  int P = blockIdx.x*256 + t;                 // global pixel 0..131071
  const float* src = (blockIdx.y == 0) ? T : C;
  int b = P >> 14, p = P & (HW-1);
  const float* base = src + (size_t)b*DIM*HW + p;
  float s = 0.f, ss = 0.f;
  for(int c = 0; c < DIM; c++){
    float v = base[(size_t)c*HW];
    s += v; ss += v*v;
  }
  float m   = s * (1.f/DIM);
  float var = ss * (1.f/DIM) - m*m;
  float rs  = rsqrtf(var + 1e-5f);
  int o = blockIdx.y*NPIX + P;
  mu[o] = m; rstd[o] = rs;
}

// ---------------- fold LN affine into conv weights (bf16 out) ----------------
// W'[o,c] = bf16(W[o,c]*lnw[c]);  c1[o] = sum_c W[o,c]*lnb[c] + convb[o];
// c2[o] = sum_c b2f(W'[o,c])  (rounded weights, so the mean-fold matches the MFMA exactly)
__global__ void k_prep(const float* tq_w, const float* ck_w, const float* cv_w,
                       const float* tq_b, const float* ck_b, const float* cv_b,
                       const float* tn_w, const float* tn_b,
                       const float* cn_w, const float* cn_b,
                       bf16* Wpb, float* c1, float* c2){
  int o = blockIdx.x, conv = blockIdx.y, t = threadIdx.x;
  const float* W  = conv==0 ? tq_w : (conv==1 ? ck_w : cv_w);
  const float* cb = conv==0 ? tq_b : (conv==1 ? ck_b : cv_b);
  const float* lw = conv==0 ? tn_w : cn_w;
  const float* lb = conv==0 ? tn_b : cn_b;
  float s1 = 0.f, s2 = 0.f;
  for(int c = t; c < DIM; c += 64){
    float w  = W[o*DIM + c];
    float wp = w * lw[c];
    bf16 wb  = f2b(wp);
    Wpb[conv*MAT + o*DIM + c] = wb;
    s1 += w * lb[c];
    s2 += b2f(wb);
  }
  for(int off = 32; off; off >>= 1){ s1 += __shfl_down(s1, off); s2 += __shfl_down(s2, off); }
  if(t == 0){ c1[conv*DIM + o] = s1 + cb[o]; c2[conv*DIM + o] = s2; }
}

// ---------------- MFMA GEMM: 128x128 tile, 4 waves (2x2), 4x4 16x16 frags, BK=32 ----
// MODE 0: out[o,p] = rs*(W' @ x)[o,p] + c1[o] - mu*rs*c2[o]  -> bf16 (LN folded; B = fp32 input)
// MODE 1: out[o,p] = (W2[b] @ v1)[o,p] + proj_b[o] + resid   -> fp32 (B = bf16 v1)
// A layout in LDS: [kb][oo][j] bf16, byte addr (kb*2048 + oo*16) ^ (kb<<5)
// B layout in LDS: [kb][pp][j] bf16, byte addr (kb*2048 + pp*16 + j*2) ^ (((pp>>3)&7)<<4)
// a_frag: lane l holds A[oo = base+(l&15)][k = (l>>4)*8 + j]; b_frag mirrored; D: col=l&15, row=(l>>4)*4+r
template<int MODE>
__global__ __launch_bounds__(256) void k_gmm(
    const float* __restrict__ Bf, const bf16* __restrict__ Bh,
    const unsigned short* __restrict__ A,
    const float* __restrict__ bias, const float* __restrict__ c2,
    const float* __restrict__ mu, const float* __restrict__ rstd,
    const float* __restrict__ resid,
    bf16* __restrict__ dsth, float* __restrict__ dstf){
  __shared__ unsigned short As[4096];   // 8 KB
  __shared__ unsigned short Bs[4096];   // 8 KB
  const int t = threadIdx.x;
  const int l = t & 63;
  const int w = t >> 6;
  const int wr = w >> 1, wc = w & 1;
  const int b = blockIdx.z;
  const int o0 = blockIdx.y*128, p0 = blockIdx.x*128;
  const unsigned short* Aw = A + (MODE==1 ? (size_t)b*MAT : (size_t)0);

  f32x4 zero = {0.f, 0.f, 0.f, 0.f};
  f32x4 acc[4][4];
  #pragma unroll
  for(int m = 0; m < 4; m++)
    #pragma unroll
    for(int n = 0; n < 4; n++) acc[m][n] = zero;

  const int a_kb = t & 3, a_o = t >> 2;   // A staging: kb 0..3, o row 0..63 (+64 round 2)
  const int b_cl = t >> 4;                // B staging: c_loc 0..15 (+16 round 2)
  const int b_p8 = (t & 15)*8;            // B staging: 8-pixel chunk
  const int kbr = l >> 4;                 // fragment k-block
  const int lr  = l & 15;

  for(int c0 = 0; c0 < DIM; c0 += 32){
    // ---- stage A (reg -> LDS, b128 writes, kb-xor keeps writes+reads ~2-way)
    #pragma unroll
    for(int r = 0; r < 2; r++){
      int oo = a_o + 64*r;
      s16x8 av = *(const s16x8*)(Aw + (size_t)(o0 + oo)*DIM + c0 + a_kb*8);
      int ad = (a_kb*2048 + oo*16) ^ (a_kb<<5);
      *(s16x8*)((char*)As + ad) = av;
    }
    // ---- stage B with transpose (coalesced global read along p, swizzled u16 scatter)
    #pragma unroll
    for(int r = 0; r < 2; r++){
      int cl = b_cl + 16*r;
      int c  = c0 + cl;
      unsigned short vals[8];
      if(MODE == 0){
        const float* src = Bf + ((size_t)(b*DIM + c))*HW + p0 + b_p8;
        float4 x0 = *(const float4*)src;
        float4 x1 = *(const float4*)(src + 4);
        vals[0]=f2bu(x0.x); vals[1]=f2bu(x0.y); vals[2]=f2bu(x0.z); vals[3]=f2bu(x0.w);
        vals[4]=f2bu(x1.x); vals[5]=f2bu(x1.y); vals[6]=f2bu(x1.z); vals[7]=f2bu(x1.w);
      } else {
        const unsigned short* src = (const unsigned short*)Bh + ((size_t)(b*DIM + c))*HW + p0 + b_p8;
        s16x8 v = *(const s16x8*)src;
        #pragma unroll
        for(int j = 0; j < 8; j++) vals[j] = (unsigned short)v[j];
      }
      int base = (cl>>3)*2048 + (cl&7)*2;
      #pragma unroll
      for(int j8 = 0; j8 < 8; j8++){
        int pp = b_p8 + j8;
        int ad = (base + pp*16) ^ (((pp>>3)&7)<<4);
        *(unsigned short*)((char*)Bs + ad) = vals[j8];
      }
    }
    __syncthreads();
    // ---- fragments + MFMA
    s16x8 af[4], bv[4];
    #pragma unroll
    for(int m = 0; m < 4; m++){
      int oo = wr*64 + m*16 + lr;
      int ad = (kbr*2048 + oo*16) ^ (kbr<<5);
      af[m] = *(const s16x8*)((const char*)As + ad);
    }
    #pragma unroll
    for(int n = 0; n < 4; n++){
      int pp = wc*64 + n*16 + lr;
      int ad = (kbr*2048 + pp*16) ^ (((pp>>3)&7)<<4);
      bv[n] = *(const s16x8*)((const char*)Bs + ad);
    }
    #pragma unroll
    for(int m = 0; m < 4; m++)
      #pragma unroll
      for(int n = 0; n < 4; n++)
        acc[m][n] = __builtin_amdgcn_mfma_f32_16x16x32_bf16(af[m], bv[n], acc[m][n], 0, 0, 0);
    __syncthreads();
  }

  // ---- epilogue (verified D layout: col = l&15, row = (l>>4)*4 + r)
  #pragma unroll
  for(int m = 0; m < 4; m++){
    int ob = o0 + wr*64 + m*16 + (l>>4)*4;
    #pragma unroll
    for(int n = 0; n < 4; n++){
      int p = p0 + wc*64 + n*16 + (l&15);
      #pragma unroll
      for(int r4 = 0; r4 < 4; r4++){
        int o = ob + r4;
        size_t oidx = ((size_t)(b*DIM + o))*HW + p;
        float v = acc[m][n][r4];
        if(MODE == 0){
          int P = b*HW + p;
          float rs = rstd[P], mm = mu[P];
          dsth[oidx] = f2b(rs*v + bias[o] - mm*rs*c2[o]);
        } else {
          dstf[oidx] = v + bias[o] + resid[oidx];
        }
      }
    }
  }
}

// ---------------- depthwise 3x3, SAME, NCHW — LDS-tiled, vectorized ----------------
// Block: 32 rows x 128 cols of one (b,c) plane. Stage 34x128 bf16 in LDS (s16x8 loads),
// each thread computes 16 outputs (2 row-segments of 8 px), vector b128 store.
// Image halo (x=-1/128, y=-1/128) is zero, handled by predication (never stored).
__global__ __launch_bounds__(256) void k_dw(const bf16* __restrict__ src, bf16* __restrict__ dst,
                                            const float* __restrict__ dw, const float* __restrict__ db,
                                            float* __restrict__ nrm){
  __shared__ unsigned short tile[34*136];   // row stride 136 shorts = 272 B (17x16B, aligned)
  __shared__ float red[4];
  int t = threadIdx.x;
  int tb = blockIdx.x;                      // row-tile 0..3
  int c = blockIdx.y, b = blockIdx.z;
  size_t base = (size_t)(b*DIM + c)*HW;
  int y0 = tb*32;
  const unsigned short* sp = (const unsigned short*)src + base;
  // stage 34 rows (y0-1 .. y0+32) x 128 cols
  for(int i = t; i < 544; i += 256){
    int r = i >> 4, ch = i & 15;
    int yy = y0 + r - 1;
    s16x8 v = {};
    if(yy >= 0 && yy < 128) v = *(const s16x8*)(sp + yy*WD + ch*8);
    *(s16x8*)&tile[r*136 + ch*8] = v;
  }
  float w[9];
  #pragma unroll
  for(int i = 0; i < 9; i++) w[i] = dw[c*9 + i];
  float bias = db[c];
  __syncthreads();
  unsigned short* dp = (unsigned short*)dst + base;
  float ssq = 0.f;
  #pragma unroll
  for(int task = 0; task < 2; task++){
    int i = t + task*256;
    int ry = i >> 4, xseg = i & 15;          // output row ry (0..31), 8-px segment
    int xb = xseg*8;
    float v[3][10];
    #pragma unroll
    for(int rr = 0; rr < 3; rr++){
      const unsigned short* row = &tile[(ry+rr)*136];
      s16x8 mid = *(const s16x8*)&row[xb];
      v[rr][0] = (xb == 0)   ? 0.f : u2f(row[xb-1]);
      #pragma unroll
      for(int j = 0; j < 8; j++) v[rr][1+j] = u2f((unsigned short)mid[j]);
      v[rr][9] = (xb == 120) ? 0.f : u2f(row[xb+8]);
    }
    s16x8 outv;
    #pragma unroll
    for(int j = 0; j < 8; j++){
      float s = bias;
      #pragma unroll
      for(int rr = 0; rr < 3; rr++){
        s = fmaf(w[rr*3+0], v[rr][j],   s);
        s = fmaf(w[rr*3+1], v[rr][j+1], s);
        s = fmaf(w[rr*3+2], v[rr][j+2], s);
      }
      ssq = fmaf(s, s, ssq);
      outv[j] = (short)f2bu(s);
    }
    *(s16x8*)(dp + (y0+ry)*WD + xb) = outv;
  }
  if(nrm){
    for(int off = 32; off; off >>= 1) ssq += __shfl_down(ssq, off);
    if((t & 63) == 0) red[t >> 6] = ssq;
    __syncthreads();
    if(t == 0) atomicAdd(&nrm[b*DIM + c], red[0]+red[1]+red[2]+red[3]);
  }
}

// ---------------- attn = q @ k^T over n, MFMA version ----------------
// attn[c][d] = sum_n q[c][n]*k[d][n]; both operands in [row][n] layout == the exact
// mfma_f32_16x16x32_bf16 fragment layout (lane l: [row=l&15][k=(l>>4)*8+j]), so
// fragments load straight from global, no staging/transpose. Grid (8 splits, NH, NB),
// 256 threads = 4 waves; wave w covers 512 n-cols (16 K=32 steps, 3x3 frags = 9 acc).
// Cross-wave reduce via LDS, then 2304 atomicAdds per block into attn.
__global__ __launch_bounds__(256) void k_attn(const bf16* __restrict__ q, const bf16* __restrict__ k,
                                              float* __restrict__ attn){
  __shared__ float part[4][48][49];
  const int t = threadIdx.x;
  const int l = t & 63;
  const int w = t >> 6;
  const int split = blockIdx.x;
  const int h = blockIdx.y, b = blockIdx.z;
  const unsigned short* qb = (const unsigned short*)q + (size_t)(b*DIM + h*NC)*HW;
  const unsigned short* kb = (const unsigned short*)k + (size_t)(b*DIM + h*NC)*HW;
  const int row = l & 15;          // fragment row within 16
  const int kch = (l >> 4)*8;      // k-chunk within K=32

  f32x4 zero = {0.f, 0.f, 0.f, 0.f};
  f32x4 acc[3][3];
  #pragma unroll
  for(int m = 0; m < 3; m++)
    #pragma unroll
    for(int n = 0; n < 3; n++) acc[m][n] = zero;

  const int n0 = split*2048 + w*512;
  for(int nn = 0; nn < 512; nn += 32){
    s16x8 qa[3], ka[3];
    #pragma unroll
    for(int m = 0; m < 3; m++)
      qa[m] = *(const s16x8*)(qb + (size_t)(m*16 + row)*HW + n0 + nn + kch);
    #pragma unroll
    for(int n = 0; n < 3; n++)
      ka[n] = *(const s16x8*)(kb + (size_t)(n*16 + row)*HW + n0 + nn + kch);
    #pragma unroll
    for(int m = 0; m < 3; m++)
      #pragma unroll
      for(int n = 0; n < 3; n++)
        acc[m][n] = __builtin_amdgcn_mfma_f32_16x16x32_bf16(qa[m], ka[n], acc[m][n], 0, 0, 0);
  }

  // write partials: D layout col=l&15, row=(l>>4)*4+r
  #pragma unroll
  for(int m = 0; m < 3; m++)
    #pragma unroll
    for(int n = 0; n < 3; n++)
      #pragma unroll
      for(int r = 0; r < 4; r++)
        part[w][m*16 + (l>>4)*4 + r][n*16 + (l&15)] = acc[m][n][r];
  __syncthreads();

  float* ab = attn + (size_t)(b*NH + h)*NC*NC;
  #pragma unroll
  for(int i = t; i < NC*NC; i += 256){
    int rr = i / NC, cc = i % NC;
    float s = part[0][rr][cc] + part[1][rr][cc] + part[2][rr][cc] + part[3][rr][cc];
    atomicAdd(&ab[i], s);
  }
}

// ---------------- P = sum_i a_i * softmax(mask_i(attn_scaled)) ----------------
__global__ void k_pmat(const float* __restrict__ attn, const float* __restrict__ nq,
                       const float* __restrict__ nk, const float* __restrict__ tptr,
                       const float* __restrict__ a1p, const float* __restrict__ a2p,
                       const float* __restrict__ a3p, const float* __restrict__ a4p,
                       float* __restrict__ P){
  int t = threadIdx.x;
  int h = blockIdx.x, b = blockIdx.y;
  __shared__ float nkv[48];
  if(t < 48) nkv[t] = fmaxf(sqrtf(nk[b*DIM + h*NC + t]), 1e-12f);
  __syncthreads();
  if(t >= 48) return;
  int c = t;
  float temp = tptr[0];
  float nqc = fmaxf(sqrtf(nq[b*DIM + h*NC + c]), 1e-12f);
  const float* row = attn + ((size_t)(b*NH + h)*NC + c)*NC;
  float r[48], s[48];
  for(int d = 0; d < 48; d++){
    float v = row[d] * temp / (nqc * nkv[d]);
    r[d] = v; s[d] = v;
  }
  // insertion sort descending (48 elems, tiny kernel)
  for(int i = 1; i < 48; i++){
    float key = s[i]; int j = i-1;
    while(j >= 0 && s[j] < key){ s[j+1] = s[j]; j--; }
    s[j+1] = key;
  }
  float m  = s[0];
  float t1 = s[23], t2 = s[31], t3 = s[35], t4 = s[37];   // k-th largest, k=24/32/36/38
  float d1 = 0.f, d2 = 0.f, d3 = 0.f, d4 = 0.f;
  for(int d = 0; d < 48; d++){
    float e = expf(r[d] - m);
    s[d] = e;                     // reuse as exp cache
    if(r[d] >= t1) d1 += e;
    if(r[d] >= t2) d2 += e;
    if(r[d] >= t3) d3 += e;
    if(r[d] >= t4) d4 += e;
  }
  float w1 = a1p[0]/d1, w2 = a2p[0]/d2, w3 = a3p[0]/d3, w4 = a4p[0]/d4;
  float* Pr = P + ((size_t)(b*NH + h)*NC + c)*NC;
  for(int d = 0; d < 48; d++){
    float wsum = 0.f;
    if(r[d] >= t1) wsum += w1;
    if(r[d] >= t2) wsum += w2;
    if(r[d] >= t3) wsum += w3;
    if(r[d] >= t4) wsum += w4;
    Pr[d] = s[d] * wsum;
  }
}

// ---------------- W2[b,o,h*48+d] = sum_c projW[o,h*48+c] * P[b,h,c,d]  (bf16 out) ----------------
__global__ __launch_bounds__(384) void k_w2(const float* __restrict__ Wp, const float* __restrict__ P,
                                            bf16* __restrict__ W2){
  int t = threadIdx.x;            // 0..383 -> (h,d)
  int o = blockIdx.x, b = blockIdx.y;
  int h = t / 48, d = t % 48;
  const float* Pb = P + (size_t)(b*NH + h)*NC*NC + d;
  const float* Wr = Wp + o*DIM + h*NC;
  float s = 0.f;
  for(int c = 0; c < 48; c++) s = fmaf(Wr[c], Pb[c*NC], s);
  W2[((size_t)b*DIM + o)*DIM + t] = f2b(s);
}

extern "C" void kernel_launch(void* const* d_in, const int* in_sizes, int n_in,
                              void* d_out, int out_size, void* d_ws, size_t ws_size,
                              hipStream_t stream){
  const float* TEin = (const float*)d_in[0];
  const float* CEin = (const float*)d_in[1];
  const float* tn_w = (const float*)d_in[2];
  const float* tn_b = (const float*)d_in[3];
  const float* cn_w = (const float*)d_in[4];
  const float* cn_b = (const float*)d_in[5];
  const float* tq_w = (const float*)d_in[6];
  const float* tq_b = (const float*)d_in[7];
  const float* tq_dw= (const float*)d_in[8];
  const float* tq_db= (const float*)d_in[9];
  const float* ck_w = (const float*)d_in[10];
  const float* ck_b = (const float*)d_in[11];
  const float* ck_dw= (const float*)d_in[12];
  const float* ck_db= (const float*)d_in[13];
  const float* cv_w = (const float*)d_in[14];
  const float* cv_b = (const float*)d_in[15];
  const float* cv_dw= (const float*)d_in[16];
  const float* cv_db= (const float*)d_in[17];
  const float* temp = (const float*)d_in[18];
  const float* pj_w = (const float*)d_in[19];
  const float* pj_b = (const float*)d_in[20];
  const float* a1   = (const float*)d_in[21];
  const float* a2   = (const float*)d_in[22];
  const float* a3   = (const float*)d_in[23];
  const float* a4   = (const float*)d_in[24];

  char* ws = (char*)d_ws;
  const size_t S2 = (size_t)NB*DIM*HW*2;       // one bf16 tensor: 100,663,296 B
  bf16* q0 = (bf16*)(ws);
  bf16* k0 = (bf16*)(ws +   S2);
  bf16* v0 = (bf16*)(ws + 2*S2);
  bf16* q1 = (bf16*)(ws + 3*S2);
  bf16* k1 = (bf16*)(ws);          // reuses q0 (dead after dw-q)
  bf16* v1 = (bf16*)(ws +   S2);   // reuses k0 (dead after dw-k)
  char* sm = ws + 4*S2;
  float* mu   = (float*)(sm);                      // 2*131072 fp32
  float* rstd = (float*)(sm + 1048576);
  bf16*  Wpb  = (bf16*) (sm + 2097152);            // 3*384*384 bf16 (fits old fp32 slot)
  float* c1   = (float*)(sm + 3866624);            // 3*384
  float* c2   = (float*)(sm + 3871232);            // 3*384
  float* nq   = (float*)(sm + 3875840);            // 8*384
  float* nk   = (float*)(sm + 3888128);            // 8*384
  float* attn = (float*)(sm + 3900416);            // 64*48*48
  float* P    = (float*)(sm + 4490240);            // 64*48*48
  bf16*  W2b  = (bf16*) (sm + 5080064);            // 8*384*384 bf16 (fits old fp32 slot)

  // zero atomic targets (nq, nk, attn are contiguous: 153600 floats)
  k_zero<<<dim3(600), 256, 0, stream>>>(nq, 153600);
  // LN stats for both tensors
  k_stats<<<dim3(512, 2), 256, 0, stream>>>(TEin, CEin, mu, rstd);
  // fold LN into conv weights (bf16)
  k_prep<<<dim3(384, 3), 64, 0, stream>>>(tq_w, ck_w, cv_w, tq_b, ck_b, cv_b,
                                          tn_w, tn_b, cn_w, cn_b, Wpb, c1, c2);
  // conv1x1 (LN folded) via MFMA: q from T stats, k/v from C stats
  k_gmm<0><<<dim3(128,3,8), 256, 0, stream>>>(TEin, nullptr, (const unsigned short*)Wpb,
                                              c1, c2, mu, rstd, nullptr, q0, nullptr);
  k_gmm<0><<<dim3(128,3,8), 256, 0, stream>>>(CEin, nullptr, (const unsigned short*)(Wpb+MAT),
                                              c1+DIM, c2+DIM, mu+NPIX, rstd+NPIX, nullptr, k0, nullptr);
  k_gmm<0><<<dim3(128,3,8), 256, 0, stream>>>(CEin, nullptr, (const unsigned short*)(Wpb+2*MAT),
                                              c1+2*DIM, c2+2*DIM, mu+NPIX, rstd+NPIX, nullptr, v0, nullptr);
  // depthwise 3x3 (+ sumsq accumulation for q,k norms), LDS-tiled
  k_dw<<<dim3(4,384,8), 256, 0, stream>>>(q0, q1, tq_dw, tq_db, nq);
  k_dw<<<dim3(4,384,8), 256, 0, stream>>>(k0, k1, ck_dw, ck_db, nk);
  k_dw<<<dim3(4,384,8), 256, 0, stream>>>(v0, v1, cv_dw, cv_db, nullptr);
  // attn (unnormalized) via MFMA, 8-way n-split, LDS wave-reduce + atomics
  k_attn<<<dim3(8,8,8), 256, 0, stream>>>(q1, k1, attn);
  // combined masked-softmax matrix P (norms + temperature folded here)
  k_pmat<<<dim3(8,8), 64, 0, stream>>>(attn, nq, nk, temp, a1, a2, a3, a4, P);
  // W2 = projW (per-head) @ P  (bf16 out)
  k_w2<<<dim3(384,8), 384, 0, stream>>>(pj_w, P, W2b);
  // fused (P·v + proj + residual) as one MFMA GEMM: out = W2[b] @ v1 + proj_b + C_E_input
  k_gmm<1><<<dim3(128,3,8), 256, 0, stream>>>(nullptr, v1, (const unsigned short*)W2b,
                                              pj_b, nullptr, nullptr, nullptr, CEin, nullptr, (float*)d_out);
}

// Round 5
// 1235.749 us; speedup vs baseline: 3.2670x; 1.0503x over previous
//
#include <hip/hip_runtime.h>
#include <hip/hip_bf16.h>
#include <math.h>

#define HW   16384
#define WD   128
#define DIM  384
#define NB   8
#define NH   8
#define NC   48
#define NPIX (NB*HW)        // 131072
#define MAT  (DIM*DIM)      // 147456

typedef __hip_bfloat16 bf16;
typedef short s16x8 __attribute__((ext_vector_type(8)));
typedef float f32x4 __attribute__((ext_vector_type(4)));

__device__ __forceinline__ float b2f(bf16 x){ return __bfloat162float(x); }
__device__ __forceinline__ bf16  f2b(float x){ return __float2bfloat16(x); }
__device__ __forceinline__ unsigned short f2bu(float x){
  bf16 b = __float2bfloat16(x);
  unsigned short u;
  __builtin_memcpy(&u, &b, 2);
  return u;
}
__device__ __forceinline__ float u2f(unsigned short u){
  union{ unsigned int i; float f; } x;
  x.i = ((unsigned int)u) << 16;
  return x.f;
}

// ---------------- zero small atomic targets ----------------
__global__ void k_zero(float* p, int n){
  int i = blockIdx.x*256 + threadIdx.x;
  if(i < n) p[i] = 0.f;
}

// ---------------- fused LayerNorm: stats + normalize -> bf16 [c][p] ----------------
// Block: 64 pixels, 256 threads (4 parts x 64 px). Stage x as bf16 in LDS (49KB)
// so pass2 needs no global re-read. Stats in fp32 from the original values.
__global__ __launch_bounds__(256) void k_ln(const float* __restrict__ T,
                                            const float* __restrict__ C,
                                            bf16* __restrict__ Tn,
                                            bf16* __restrict__ Cn){
  __shared__ unsigned short xs[DIM*64];        // [c][px], 49152 B
  __shared__ float sred[4][64], ssred[4][64];
  __shared__ float mv[64], rv[64];
  int t = threadIdx.x;
  int px = t & 63, part = t >> 6;
  int P = blockIdx.x*64 + px;
  const float* src = (blockIdx.y == 0) ? T : C;
  bf16* dst = (blockIdx.y == 0) ? Tn : Cn;
  int b = P >> 14, p = P & (HW-1);
  const float* base = src + (size_t)b*DIM*HW + p;
  float s = 0.f, ss = 0.f;
  for(int c = part*96; c < part*96 + 96; c++){
    float v = base[(size_t)c*HW];
    s += v; ss += v*v;
    xs[c*64 + px] = f2bu(v);
  }
  sred[part][px] = s; ssred[part][px] = ss;
  __syncthreads();
  if(t < 64){
    float S  = sred[0][t]+sred[1][t]+sred[2][t]+sred[3][t];
    float SS = ssred[0][t]+ssred[1][t]+ssred[2][t]+ssred[3][t];
    float m  = S * (1.f/DIM);
    float var = SS * (1.f/DIM) - m*m;
    mv[t] = m; rv[t] = rsqrtf(var + 1e-5f);
  }
  __syncthreads();
  float m = mv[px], rs = rv[px];
  bf16* ob = dst + (size_t)b*DIM*HW + p;
  for(int c = part*96; c < part*96 + 96; c++){
    float v = u2f(xs[c*64 + px]);
    ob[(size_t)c*HW] = f2b((v - m)*rs);
  }
}

// ---------------- fold LN affine into conv weights (bf16 out) ----------------
// W'[o,c] = bf16(W[o,c]*lnw[c]);  c1[o] = sum_c W[o,c]*lnb[c] + convb[o]
// (input to the GEMM is the mean-free normalized xn, so no mean correction needed)
__global__ void k_prep(const float* tq_w, const float* ck_w, const float* cv_w,
                       const float* tq_b, const float* ck_b, const float* cv_b,
                       const float* tn_w, const float* tn_b,
                       const float* cn_w, const float* cn_b,
                       bf16* Wpb, float* c1){
  int o = blockIdx.x, conv = blockIdx.y, t = threadIdx.x;
  const float* W  = conv==0 ? tq_w : (conv==1 ? ck_w : cv_w);
  const float* cb = conv==0 ? tq_b : (conv==1 ? ck_b : cv_b);
  const float* lw = conv==0 ? tn_w : cn_w;
  const float* lb = conv==0 ? tn_b : cn_b;
  float s1 = 0.f;
  for(int c = t; c < DIM; c += 64){
    float w  = W[o*DIM + c];
    Wpb[conv*MAT + o*DIM + c] = f2b(w * lw[c]);
    s1 += w * lb[c];
  }
  for(int off = 32; off; off >>= 1) s1 += __shfl_down(s1, off);
  if(t == 0) c1[conv*DIM + o] = s1 + cb[o];
}

// ---------------- MFMA GEMM: 128x128 tile, 4 waves (2x2), 4x4 16x16 frags, BK=32 ----
// B input is always bf16 [c][p]. MODE 0: out = acc + bias -> bf16.
// MODE 1: out = acc + bias + resid -> fp32 (A indexed per-batch).
// A LDS: [kb][oo][j] bf16, byte addr (kb*2048 + oo*16) ^ (kb<<5)
// B LDS: [kb][pp][j] bf16, byte addr (kb*2048 + pp*16 + j*2) ^ (((pp>>3)&7)<<4)
// B staged 2 channels/thread -> paired b32 writes (2-way banks, free).
template<int MODE>
__global__ __launch_bounds__(256) void k_gmm(
    const bf16* __restrict__ Bh, const unsigned short* __restrict__ A,
    const float* __restrict__ bias, const float* __restrict__ resid,
    bf16* __restrict__ dsth, float* __restrict__ dstf){
  __shared__ unsigned short As[4096];   // 8 KB
  __shared__ unsigned short Bs[4096];   // 8 KB
  const int t = threadIdx.x;
  const int l = t & 63;
  const int w = t >> 6;
  const int wr = w >> 1, wc = w & 1;
  const int b = blockIdx.z;
  const int o0 = blockIdx.y*128, p0 = blockIdx.x*128;
  const unsigned short* Aw = A + (MODE==1 ? (size_t)b*MAT : (size_t)0);

  f32x4 zero = {0.f, 0.f, 0.f, 0.f};
  f32x4 acc[4][4];
  #pragma unroll
  for(int m = 0; m < 4; m++)
    #pragma unroll
    for(int n = 0; n < 4; n++) acc[m][n] = zero;

  const int a_kb = t & 3, a_o = t >> 2;   // A staging: kb 0..3, o row 0..63 (+64 round 2)
  const int b_cp = (t >> 4)*2;            // B staging: channel pair 0,2,..,30
  const int b_p8 = (t & 15)*8;            // B staging: 8-pixel chunk
  const int kbr = l >> 4;                 // fragment k-block
  const int lr  = l & 15;

  for(int c0 = 0; c0 < DIM; c0 += 32){
    // ---- stage A (2 x b128 writes, kb-xor keeps writes+reads ~2-way)
    #pragma unroll
    for(int r = 0; r < 2; r++){
      int oo = a_o + 64*r;
      s16x8 av = *(const s16x8*)(Aw + (size_t)(o0 + oo)*DIM + c0 + a_kb*8);
      int ad = (a_kb*2048 + oo*16) ^ (a_kb<<5);
      *(s16x8*)((char*)As + ad) = av;
    }
    // ---- stage B: 2 channels/thread (coalesced s16x8 global), 8 paired b32 LDS writes
    {
      const unsigned short* src = (const unsigned short*)Bh
          + ((size_t)(b*DIM + c0 + b_cp))*HW + p0 + b_p8;
      s16x8 v0 = *(const s16x8*)src;
      s16x8 v1 = *(const s16x8*)(src + HW);
      int kb = b_cp >> 3, j = b_cp & 7;
      int basead = kb*2048 + j*2;
      #pragma unroll
      for(int j8 = 0; j8 < 8; j8++){
        int pp = b_p8 + j8;
        int ad = (basead + pp*16) ^ (((pp>>3)&7)<<4);
        unsigned int pk = (unsigned int)(unsigned short)v0[j8]
                        | ((unsigned int)(unsigned short)v1[j8] << 16);
        *(unsigned int*)((char*)Bs + ad) = pk;
      }
    }
    __syncthreads();
    // ---- fragments + MFMA
    s16x8 af[4], bv[4];
    #pragma unroll
    for(int m = 0; m < 4; m++){
      int oo = wr*64 + m*16 + lr;
      int ad = (kbr*2048 + oo*16) ^ (kbr<<5);
      af[m] = *(const s16x8*)((const char*)As + ad);
    }
    #pragma unroll
    for(int n = 0; n < 4; n++){
      int pp = wc*64 + n*16 + lr;
      int ad = (kbr*2048 + pp*16) ^ (((pp>>3)&7)<<4);
      bv[n] = *(const s16x8*)((const char*)Bs + ad);
    }
    #pragma unroll
    for(int m = 0; m < 4; m++)
      #pragma unroll
      for(int n = 0; n < 4; n++)
        acc[m][n] = __builtin_amdgcn_mfma_f32_16x16x32_bf16(af[m], bv[n], acc[m][n], 0, 0, 0);
    __syncthreads();
  }

  // ---- epilogue (verified D layout: col = l&15, row = (l>>4)*4 + r)
  #pragma unroll
  for(int m = 0; m < 4; m++){
    int ob = o0 + wr*64 + m*16 + (l>>4)*4;
    #pragma unroll
    for(int n = 0; n < 4; n++){
      int p = p0 + wc*64 + n*16 + (l&15);
      #pragma unroll
      for(int r4 = 0; r4 < 4; r4++){
        int o = ob + r4;
        size_t oidx = ((size_t)(b*DIM + o))*HW + p;
        float v = acc[m][n][r4] + bias[o];
        if(MODE == 0) dsth[oidx] = f2b(v);
        else          dstf[oidx] = v + resid[oidx];
      }
    }
  }
}

// ---------------- depthwise 3x3, SAME, NCHW — LDS-tiled, vectorized ----------------
__global__ __launch_bounds__(256) void k_dw(const bf16* __restrict__ src, bf16* __restrict__ dst,
                                            const float* __restrict__ dw, const float* __restrict__ db,
                                            float* __restrict__ nrm){
  __shared__ unsigned short tile[34*136];   // row stride 136 shorts = 272 B (17x16B, aligned)
  __shared__ float red[4];
  int t = threadIdx.x;
  int tb = blockIdx.x;                      // row-tile 0..3
  int c = blockIdx.y, b = blockIdx.z;
  size_t base = (size_t)(b*DIM + c)*HW;
  int y0 = tb*32;
  const unsigned short* sp = (const unsigned short*)src + base;
  for(int i = t; i < 544; i += 256){
    int r = i >> 4, ch = i & 15;
    int yy = y0 + r - 1;
    s16x8 v = {};
    if(yy >= 0 && yy < 128) v = *(const s16x8*)(sp + yy*WD + ch*8);
    *(s16x8*)&tile[r*136 + ch*8] = v;
  }
  float w[9];
  #pragma unroll
  for(int i = 0; i < 9; i++) w[i] = dw[c*9 + i];
  float bias = db[c];
  __syncthreads();
  unsigned short* dp = (unsigned short*)dst + base;
  float ssq = 0.f;
  #pragma unroll
  for(int task = 0; task < 2; task++){
    int i = t + task*256;
    int ry = i >> 4, xseg = i & 15;
    int xb = xseg*8;
    float v[3][10];
    #pragma unroll
    for(int rr = 0; rr < 3; rr++){
      const unsigned short* row = &tile[(ry+rr)*136];
      s16x8 mid = *(const s16x8*)&row[xb];
      v[rr][0] = (xb == 0)   ? 0.f : u2f(row[xb-1]);
      #pragma unroll
      for(int j = 0; j < 8; j++) v[rr][1+j] = u2f((unsigned short)mid[j]);
      v[rr][9] = (xb == 120) ? 0.f : u2f(row[xb+8]);
    }
    s16x8 outv;
    #pragma unroll
    for(int j = 0; j < 8; j++){
      float s = bias;
      #pragma unroll
      for(int rr = 0; rr < 3; rr++){
        s = fmaf(w[rr*3+0], v[rr][j],   s);
        s = fmaf(w[rr*3+1], v[rr][j+1], s);
        s = fmaf(w[rr*3+2], v[rr][j+2], s);
      }
      ssq = fmaf(s, s, ssq);
      outv[j] = (short)f2bu(s);
    }
    *(s16x8*)(dp + (y0+ry)*WD + xb) = outv;
  }
  if(nrm){
    for(int off = 32; off; off >>= 1) ssq += __shfl_down(ssq, off);
    if((t & 63) == 0) red[t >> 6] = ssq;
    __syncthreads();
    if(t == 0) atomicAdd(&nrm[b*DIM + c], red[0]+red[1]+red[2]+red[3]);
  }
}

// ---------------- attn = q @ k^T over n, MFMA, direct-from-global fragments ----------------
__global__ __launch_bounds__(256) void k_attn(const bf16* __restrict__ q, const bf16* __restrict__ k,
                                              float* __restrict__ attn){
  __shared__ float part[4][48][49];
  const int t = threadIdx.x;
  const int l = t & 63;
  const int w = t >> 6;
  const int split = blockIdx.x;
  const int h = blockIdx.y, b = blockIdx.z;
  const unsigned short* qb = (const unsigned short*)q + (size_t)(b*DIM + h*NC)*HW;
  const unsigned short* kb = (const unsigned short*)k + (size_t)(b*DIM + h*NC)*HW;
  const int row = l & 15;
  const int kch = (l >> 4)*8;

  f32x4 zero = {0.f, 0.f, 0.f, 0.f};
  f32x4 acc[3][3];
  #pragma unroll
  for(int m = 0; m < 3; m++)
    #pragma unroll
    for(int n = 0; n < 3; n++) acc[m][n] = zero;

  const int n0 = split*2048 + w*512;
  for(int nn = 0; nn < 512; nn += 32){
    s16x8 qa[3], ka[3];
    #pragma unroll
    for(int m = 0; m < 3; m++)
      qa[m] = *(const s16x8*)(qb + (size_t)(m*16 + row)*HW + n0 + nn + kch);
    #pragma unroll
    for(int n = 0; n < 3; n++)
      ka[n] = *(const s16x8*)(kb + (size_t)(n*16 + row)*HW + n0 + nn + kch);
    #pragma unroll
    for(int m = 0; m < 3; m++)
      #pragma unroll
      for(int n = 0; n < 3; n++)
        acc[m][n] = __builtin_amdgcn_mfma_f32_16x16x32_bf16(qa[m], ka[n], acc[m][n], 0, 0, 0);
  }

  #pragma unroll
  for(int m = 0; m < 3; m++)
    #pragma unroll
    for(int n = 0; n < 3; n++)
      #pragma unroll
      for(int r = 0; r < 4; r++)
        part[w][m*16 + (l>>4)*4 + r][n*16 + (l&15)] = acc[m][n][r];
  __syncthreads();

  float* ab = attn + (size_t)(b*NH + h)*NC*NC;
  #pragma unroll
  for(int i = t; i < NC*NC; i += 256){
    int rr = i / NC, cc = i % NC;
    float s = part[0][rr][cc] + part[1][rr][cc] + part[2][rr][cc] + part[3][rr][cc];
    atomicAdd(&ab[i], s);
  }
}

// ---------------- P = sum_i a_i * softmax(mask_i(attn_scaled)) ----------------
__global__ void k_pmat(const float* __restrict__ attn, const float* __restrict__ nq,
                       const float* __restrict__ nk, const float* __restrict__ tptr,
                       const float* __restrict__ a1p, const float* __restrict__ a2p,
                       const float* __restrict__ a3p, const float* __restrict__ a4p,
                       float* __restrict__ P){
  int t = threadIdx.x;
  int h = blockIdx.x, b = blockIdx.y;
  __shared__ float nkv[48];
  if(t < 48) nkv[t] = fmaxf(sqrtf(nk[b*DIM + h*NC + t]), 1e-12f);
  __syncthreads();
  if(t >= 48) return;
  int c = t;
  float temp = tptr[0];
  float nqc = fmaxf(sqrtf(nq[b*DIM + h*NC + c]), 1e-12f);
  const float* row = attn + ((size_t)(b*NH + h)*NC + c)*NC;
  float r[48], s[48];
  for(int d = 0; d < 48; d++){
    float v = row[d] * temp / (nqc * nkv[d]);
    r[d] = v; s[d] = v;
  }
  for(int i = 1; i < 48; i++){
    float key = s[i]; int j = i-1;
    while(j >= 0 && s[j] < key){ s[j+1] = s[j]; j--; }
    s[j+1] = key;
  }
  float m  = s[0];
  float t1 = s[23], t2 = s[31], t3 = s[35], t4 = s[37];
  float d1 = 0.f, d2 = 0.f, d3 = 0.f, d4 = 0.f;
  for(int d = 0; d < 48; d++){
    float e = expf(r[d] - m);
    s[d] = e;
    if(r[d] >= t1) d1 += e;
    if(r[d] >= t2) d2 += e;
    if(r[d] >= t3) d3 += e;
    if(r[d] >= t4) d4 += e;
  }
  float w1 = a1p[0]/d1, w2 = a2p[0]/d2, w3 = a3p[0]/d3, w4 = a4p[0]/d4;
  float* Pr = P + ((size_t)(b*NH + h)*NC + c)*NC;
  for(int d = 0; d < 48; d++){
    float wsum = 0.f;
    if(r[d] >= t1) wsum += w1;
    if(r[d] >= t2) wsum += w2;
    if(r[d] >= t3) wsum += w3;
    if(r[d] >= t4) wsum += w4;
    Pr[d] = s[d] * wsum;
  }
}

// ---------------- W2[b,o,h*48+d] = sum_c projW[o,h*48+c] * P[b,h,c,d]  (bf16 out) ----------------
__global__ __launch_bounds__(384) void k_w2(const float* __restrict__ Wp, const float* __restrict__ P,
                                            bf16* __restrict__ W2){
  int t = threadIdx.x;
  int o = blockIdx.x, b = blockIdx.y;
  int h = t / 48, d = t % 48;
  const float* Pb = P + (size_t)(b*NH + h)*NC*NC + d;
  const float* Wr = Wp + o*DIM + h*NC;
  float s = 0.f;
  for(int c = 0; c < 48; c++) s = fmaf(Wr[c], Pb[c*NC], s);
  W2[((size_t)b*DIM + o)*DIM + t] = f2b(s);
}

extern "C" void kernel_launch(void* const* d_in, const int* in_sizes, int n_in,
                              void* d_out, int out_size, void* d_ws, size_t ws_size,
                              hipStream_t stream){
  const float* TEin = (const float*)d_in[0];
  const float* CEin = (const float*)d_in[1];
  const float* tn_w = (const float*)d_in[2];
  const float* tn_b = (const float*)d_in[3];
  const float* cn_w = (const float*)d_in[4];
  const float* cn_b = (const float*)d_in[5];
  const float* tq_w = (const float*)d_in[6];
  const float* tq_b = (const float*)d_in[7];
  const float* tq_dw= (const float*)d_in[8];
  const float* tq_db= (const float*)d_in[9];
  const float* ck_w = (const float*)d_in[10];
  const float* ck_b = (const float*)d_in[11];
  const float* ck_dw= (const float*)d_in[12];
  const float* ck_db= (const float*)d_in[13];
  const float* cv_w = (const float*)d_in[14];
  const float* cv_b = (const float*)d_in[15];
  const float* cv_dw= (const float*)d_in[16];
  const float* cv_db= (const float*)d_in[17];
  const float* temp = (const float*)d_in[18];
  const float* pj_w = (const float*)d_in[19];
  const float* pj_b = (const float*)d_in[20];
  const float* a1   = (const float*)d_in[21];
  const float* a2   = (const float*)d_in[22];
  const float* a3   = (const float*)d_in[23];
  const float* a4   = (const float*)d_in[24];

  char* ws = (char*)d_ws;
  const size_t S2 = (size_t)NB*DIM*HW*2;       // one bf16 tensor: 100,663,296 B
  // 4-slot buffer choreography:
  //   A=Tn -> q1;  B=k0 -> v1;  C=v0;  D=Cn -> q0 -> k1
  bf16* bufA = (bf16*)(ws);
  bf16* bufB = (bf16*)(ws +   S2);
  bf16* bufC = (bf16*)(ws + 2*S2);
  bf16* bufD = (bf16*)(ws + 3*S2);
  char* sm = ws + 4*S2;
  bf16*  Wpb  = (bf16*) (sm + 2097152);            // 3*384*384 bf16
  float* c1   = (float*)(sm + 3866624);            // 3*384
  float* nq   = (float*)(sm + 3875840);            // 8*384
  float* nk   = (float*)(sm + 3888128);            // 8*384
  float* attn = (float*)(sm + 3900416);            // 64*48*48
  float* P    = (float*)(sm + 4490240);            // 64*48*48
  bf16*  W2b  = (bf16*) (sm + 5080064);            // 8*384*384 bf16

  // zero atomic targets (nq, nk, attn are contiguous: 153600 floats)
  k_zero<<<dim3(600), 256, 0, stream>>>(nq, 153600);
  // fused LN -> normalized bf16 tensors: Tn=A, Cn=D
  k_ln<<<dim3(2048, 2), 256, 0, stream>>>(TEin, CEin, bufA, bufD);
  // fold LN affine into conv weights (bf16)
  k_prep<<<dim3(384, 3), 64, 0, stream>>>(tq_w, ck_w, cv_w, tq_b, ck_b, cv_b,
                                          tn_w, tn_b, cn_w, cn_b, Wpb, c1);
  // conv1x1 via MFMA on normalized bf16: k,v from Cn(D); q from Tn(A) -> D (Cn dead)
  k_gmm<0><<<dim3(128,3,8), 256, 0, stream>>>(bufD, (const unsigned short*)(Wpb+MAT),
                                              c1+DIM, nullptr, bufB, nullptr);
  k_gmm<0><<<dim3(128,3,8), 256, 0, stream>>>(bufD, (const unsigned short*)(Wpb+2*MAT),
                                              c1+2*DIM, nullptr, bufC, nullptr);
  k_gmm<0><<<dim3(128,3,8), 256, 0, stream>>>(bufA, (const unsigned short*)Wpb,
                                              c1, nullptr, bufD, nullptr);
  // depthwise 3x3 (+ sumsq for l2 norms): q D->A, k B->D, v C->B
  k_dw<<<dim3(4,384,8), 256, 0, stream>>>(bufD, bufA, tq_dw, tq_db, nq);
  k_dw<<<dim3(4,384,8), 256, 0, stream>>>(bufB, bufD, ck_dw, ck_db, nk);
  k_dw<<<dim3(4,384,8), 256, 0, stream>>>(bufC, bufB, cv_dw, cv_db, nullptr);
  // attn (unnormalized) via MFMA: q1=A, k1=D
  k_attn<<<dim3(8,8,8), 256, 0, stream>>>(bufA, bufD, attn);
  // combined masked-softmax matrix P (norms + temperature folded here)
  k_pmat<<<dim3(8,8), 64, 0, stream>>>(attn, nq, nk, temp, a1, a2, a3, a4, P);
  // W2 = projW (per-head) @ P  (bf16 out)
  k_w2<<<dim3(384,8), 384, 0, stream>>>(pj_w, P, W2b);
  // fused (P·v + proj + residual): out = W2[b] @ v1(B) + proj_b + C_E_input
  k_gmm<1><<<dim3(128,3,8), 256, 0, stream>>>(bufB, (const unsigned short*)W2b,
                                              pj_b, CEin, nullptr, (float*)d_out);
}